// Round 13
// baseline (133.350 us; speedup 1.0000x reference)
//
#include <hip/hip_runtime.h>

typedef _Float16 f16;
typedef _Float16 f16x2 __attribute__((ext_vector_type(2)));
typedef _Float16 f16x4 __attribute__((ext_vector_type(4)));
typedef _Float16 f16x8 __attribute__((ext_vector_type(8)));
typedef float f32x4 __attribute__((ext_vector_type(4)));
typedef float f32x16 __attribute__((ext_vector_type(16)));

#define MFMA16(a, b, c) __builtin_amdgcn_mfma_f32_16x16x32_f16((a), (b), (c), 0, 0, 0)
#define MFMA32(a, b, c) __builtin_amdgcn_mfma_f32_32x32x16_f16((a), (b), (c), 0, 0, 0)

typedef const __attribute__((address_space(1))) void gv_t;
typedef __attribute__((address_space(3))) void lv_t;

// ---------------- fused fp32 -> f16 convert (x, qkv_w, out_w in one launch) ------
__global__ void cvt_all(const float* __restrict__ x, const float* __restrict__ qw,
                        const float* __restrict__ ow, f16* __restrict__ d) {
    int i = (blockIdx.x * 256 + threadIdx.x) * 4;   // flat f16-element index / 4
    const float* s;
    int off;
    if (i < 4194304) { s = x; off = i; }
    else if (i < 4980736) { s = qw; off = i - 4194304; }
    else { s = ow; off = i - 4980736; }
    float4 v = *(const float4*)(s + off);
    f16x4 o = {(f16)v.x, (f16)v.y, (f16)v.z, (f16)v.w};
    *(f16x4*)(d + i) = o;
}

// ---------------- NT GEMM, 128x128 tile, BK=32, dbuf LDS via global_load_lds ----
// MODE 0 epilogue packs K and V into MFMA-fragment-major layouts:
//   Kp[b][kb=s>>5][kc=d>>4][lane=(d>>3&1)*32+(s&31)][e=d&7]
//   Vp[b][db=d>>5][kw=s>>4][lane=(s>>3&1)*32+(d&31)][e=s&7]
template<int MODE>
__global__ __launch_bounds__(256, 3) void gemm_nt(const f16* __restrict__ A, const f16* __restrict__ W,
                                                  const float* __restrict__ bias, float* __restrict__ Cf,
                                                  f16* __restrict__ Qb, f16* __restrict__ Kb,
                                                  f16* __restrict__ Vt) {
    __shared__ f16 As[2][128 * 32];
    __shared__ f16 Bs[2][128 * 32];
    const int m0 = blockIdx.x * 128, n0 = blockIdx.y * 128;
    const int tid = threadIdx.x;
    const int w = tid >> 6, l = tid & 63;
    const int wm = w >> 1, wn = w & 1;
    const int lr = l & 15, lg = l >> 4;
    const int R = w * 16 + (l >> 2);
    const int ldsoff = w * 512;
    const int lidx = ldsoff + l * 8;
    const f16* ag = A + (size_t)(m0 + R) * 512 + (l & 3) * 8;
    const f16* bg = W + (size_t)(n0 + R) * 512 + (l & 3) * 8;
    (void)lidx;

#if __has_builtin(__builtin_amdgcn_global_load_lds)
#define GLDS(gp, lp) __builtin_amdgcn_global_load_lds((gv_t*)(gp), (lv_t*)(lp), 16, 0, 0)
#define STAGE(k0, buf) do {                                   \
        GLDS(ag + (k0), &As[buf][ldsoff]);                    \
        GLDS(ag + 64 * 512 + (k0), &As[buf][ldsoff + 2048]);  \
        GLDS(bg + (k0), &Bs[buf][ldsoff]);                    \
        GLDS(bg + 64 * 512 + (k0), &Bs[buf][ldsoff + 2048]);  \
    } while (0)
#else
#define STAGE(k0, buf) do {                                                      \
        *(f16x8*)&As[buf][lidx] = *(const f16x8*)(ag + (k0));                    \
        *(f16x8*)&As[buf][lidx + 2048] = *(const f16x8*)(ag + 64 * 512 + (k0));  \
        *(f16x8*)&Bs[buf][lidx] = *(const f16x8*)(bg + (k0));                    \
        *(f16x8*)&Bs[buf][lidx + 2048] = *(const f16x8*)(bg + 64 * 512 + (k0));  \
    } while (0)
#endif

    f32x4 acc[4][4] = {};
    STAGE(0, 0);
    __syncthreads();
    int cur = 0;
    for (int k0 = 0; k0 < 512; k0 += 32) {
        if (k0 + 32 < 512) STAGE(k0 + 32, cur ^ 1);
        f16x8 af[4], bf[4];
#pragma unroll
        for (int i = 0; i < 4; ++i) af[i] = *(f16x8*)&As[cur][(64 * wm + 16 * i + lr) * 32 + lg * 8];
#pragma unroll
        for (int i = 0; i < 4; ++i) bf[i] = *(f16x8*)&Bs[cur][(64 * wn + 16 * i + lr) * 32 + lg * 8];
        __builtin_amdgcn_s_setprio(1);
#pragma unroll
        for (int mf = 0; mf < 4; ++mf)
#pragma unroll
            for (int nf = 0; nf < 4; ++nf) acc[mf][nf] = MFMA16(af[mf], bf[nf], acc[mf][nf]);
        __builtin_amdgcn_s_setprio(0);
        __syncthreads();
        cur ^= 1;
    }
#pragma unroll
    for (int mf = 0; mf < 4; ++mf)
#pragma unroll
        for (int nf = 0; nf < 4; ++nf)
#pragma unroll
            for (int r = 0; r < 4; ++r) {
                int rr = 64 * wm + 16 * mf + 4 * lg + r;
                int cc = 64 * wn + 16 * nf + lr;
                int m = m0 + rr, e = n0 + cc;
                float val = acc[mf][nf][r] + bias[e];
                if (MODE == 0) {
                    int bb = m >> 11, s = m & 2047;
                    if (e < 512) {
                        Qb[((size_t)bb * 2048 + s) * 512 + e] = (f16)(val * 0.04419417382415922f);
                    } else if (e < 1024) {
                        int d = e - 512;
                        Kb[((((size_t)bb * 64 + (s >> 5)) * 32 + (d >> 4)) * 64
                            + ((d >> 3) & 1) * 32 + (s & 31)) * 8 + (d & 7)] = (f16)val;
                    } else {
                        int d = e - 1024;
                        Vt[((((size_t)bb * 16 + (d >> 5)) * 128 + (s >> 4)) * 64
                            + ((s >> 3) & 1) * 32 + (d & 31)) * 8 + (s & 7)] = (f16)val;
                    }
                } else {
                    Cf[(size_t)m * 512 + e] = val;
                }
            }
#undef STAGE
}

// ---------------- flash attention: 8 waves, QBLK=64, KEYTILE=256, 32x32 MFMA ----
// In-register K/V reuse: each K frag feeds 2 q-halves (sA0/sA1), each V frag
// feeds both O halves -> L2 traffic halved vs QBLK=32 at same per-wave loads.
// Two softmax states per lane (rows q and q+32). K ring depth 8, V pair ring.
template<int NSPLIT, bool PART>
__global__ __launch_bounds__(512, 2) void flash_attn(const f16* __restrict__ Qb, const f16* __restrict__ Kb,
                                                     const f16* __restrict__ Vt, f16* __restrict__ AO,
                                                     f16* __restrict__ Opart, float* __restrict__ Ml) {
    __shared__ f16 Qs[64 * 512];   // [row][chunk^(row&7)] on 16B chunks, 64KB
    __shared__ f16 P_lds[64 * 256];
    __shared__ float mbuf[64][8];
    __shared__ float lbuf[64][8];
    __shared__ float abuf[64];

    const int bid = blockIdx.x;
    const int xcd = bid & 7, slot = bid >> 3;
    const int b = xcd >> 1;
    const int t = slot * 2 + (xcd & 1);      // 0 .. 32*NSPLIT-1
    const int q0 = (t / NSPLIT) * 64;
    const int ks = t % NSPLIT;
    const int SPLITLEN = 2048 / NSPLIT;
    const int nkt = SPLITLEN / 256;

    const int tid = threadIdx.x;
    const int j = tid >> 6, l = tid & 63;
    const int q = l & 31, lh = l >> 5;

    const f16* Qg = Qb + ((size_t)b * 2048 + q0) * 512;
    const f16* Kg = Kb + ((size_t)b * 64 + (size_t)ks * (SPLITLEN / 32)) * 32 * 512;
    const f16* Vg = Vt + (size_t)b * 16 * 128 * 512 + (size_t)(ks * (SPLITLEN / 16)) * 512;

    // stage Q tile [64][512] into swizzled LDS (coalesced 16B per lane)
    for (int i = tid; i < 4096; i += 512) {
        int r = i >> 6, ch = i & 63;
        *(f16x8*)&Qs[r * 512 + ((ch ^ (r & 7)) * 8)] = *(const f16x8*)&Qg[(size_t)r * 512 + ch * 8];
    }

    f32x16 o[4] = {};
    float m0_st = -1e30f, l0_st = 0.f;
    float m1_st = -1e30f, l1_st = 0.f;
    char* Pq = (char*)&P_lds[0];
    const uint swz = ((uint)(q & 15)) << 4;
    const int qb0 = q * 512, qb1 = (q + 32) * 512, qx = q & 7;
    f16x8 kr[8], vr[8];
    // prologue: K batch for kt=0
    {
        const f16* kp0 = Kg + (size_t)j * 32 * 512 + (size_t)l * 8;
#pragma unroll
        for (int i = 0; i < 8; ++i) kr[i] = *(const f16x8*)(kp0 + (size_t)i * 512);
    }
    __syncthreads();

    for (int kt = 0; kt < nkt; ++kt) {
        const int key0 = kt * 256;
        const f16* kp = Kg + ((size_t)((key0 >> 5) + j) * 32) * 512 + (size_t)l * 8;
        const f16* vpb = Vg + ((size_t)(2 * j) * 128 + (key0 >> 4)) * 512 + (size_t)l * 8;
        // ---- V batch for this kt (in flight across QK^T + softmax) ----
#pragma unroll
        for (int i = 0; i < 4; ++i) {
            vr[2 * i] = *(const f16x8*)(vpb + (size_t)i * 512);
            vr[2 * i + 1] = *(const f16x8*)(vpb + (size_t)(128 + i) * 512);
        }
        // ---- QK^T (swapped): S^T[32 keys j-slice][64 q]; each K frag used 2x ----
        f32x16 sA0 = {}, sA1 = {};
        __builtin_amdgcn_s_setprio(1);
#pragma unroll
        for (int kc = 0; kc < 32; ++kc) {
            f16x8 kf = kr[kc & 7];
            if (kc < 24) kr[kc & 7] = *(const f16x8*)(kp + (size_t)(kc + 8) * 512);
            f16x8 qf0 = *(f16x8*)&Qs[qb0 + (((2 * kc + lh) ^ qx) * 8)];
            f16x8 qf1 = *(f16x8*)&Qs[qb1 + (((2 * kc + lh) ^ qx) * 8)];
            sA0 = MFMA32(kf, qf0, sA0);
            sA1 = MFMA32(kf, qf1, sA1);
        }
        __builtin_amdgcn_s_setprio(0);
        float s0[16], s1[16];
#pragma unroll
        for (int r = 0; r < 16; ++r) { s0[r] = sA0[r]; s1[r] = sA1[r]; }
        // ---- in-register partial max over own 32 keys, both q-halves ----
        float mt0 = s0[0], mt1 = s1[0];
#pragma unroll
        for (int r = 1; r < 16; ++r) { mt0 = fmaxf(mt0, s0[r]); mt1 = fmaxf(mt1, s1[r]); }
        mt0 = fmaxf(mt0, __shfl_xor(mt0, 32));
        mt1 = fmaxf(mt1, __shfl_xor(mt1, 32));
        if (l < 32) { mbuf[q][j] = mt0; mbuf[q + 32][j] = mt1; }
        __syncthreads();  // barrier 1
        float mnew0 = m0_st, mnew1 = m1_st;
        {
            float4 a = *(float4*)&mbuf[q][0], c = *(float4*)&mbuf[q][4];
            mnew0 = fmaxf(mnew0, fmaxf(fmaxf(a.x, a.y), fmaxf(a.z, a.w)));
            mnew0 = fmaxf(mnew0, fmaxf(fmaxf(c.x, c.y), fmaxf(c.z, c.w)));
            float4 d = *(float4*)&mbuf[q + 32][0], e = *(float4*)&mbuf[q + 32][4];
            mnew1 = fmaxf(mnew1, fmaxf(fmaxf(d.x, d.y), fmaxf(d.z, d.w)));
            mnew1 = fmaxf(mnew1, fmaxf(fmaxf(e.x, e.y), fmaxf(e.z, e.w)));
        }
        float alpha0 = __expf(m0_st - mnew0);
        float alpha1 = __expf(m1_st - mnew1);
        if (l < 32) { abuf[q] = alpha0; abuf[q + 32] = alpha1; }
        float ps0 = 0.f, ps1 = 0.f;
#pragma unroll
        for (int r = 0; r < 16; ++r) {
            s0[r] = __expf(s0[r] - mnew0);
            ps0 += s0[r];
            s1[r] = __expf(s1[r] - mnew1);
            ps1 += s1[r];
        }
        ps0 += __shfl_xor(ps0, 32);
        ps1 += __shfl_xor(ps1, 32);
        if (l < 32) { lbuf[q][j] = ps0; lbuf[q + 32][j] = ps1; }
        // pack P -> P_lds[row][key], XOR-swizzled, f16x4 chunks (keys 8i+4lh+32j)
        {
            const uint rowb0 = (uint)q * 512;
            const uint rowb1 = (uint)(q + 32) * 512;
#pragma unroll
            for (int i = 0; i < 4; ++i) {
                int key = 8 * i + 4 * lh + 32 * j;
                f16x4 pk0 = {(f16)s0[4 * i], (f16)s0[4 * i + 1], (f16)s0[4 * i + 2], (f16)s0[4 * i + 3]};
                f16x4 pk1 = {(f16)s1[4 * i], (f16)s1[4 * i + 1], (f16)s1[4 * i + 2], (f16)s1[4 * i + 3]};
                *(f16x4*)(Pq + ((rowb0 + (uint)key * 2) ^ swz)) = pk0;
                *(f16x4*)(Pq + ((rowb1 + (uint)key * 2) ^ swz)) = pk1;
            }
        }
        m0_st = mnew0;
        m1_st = mnew1;
        __syncthreads();  // barrier 2
        // ---- pipelined K batch for kt+1 (hidden under rescale + PV) ----
        if (kt + 1 < nkt) {
            const f16* kpn = Kg + ((size_t)(((key0 + 256) >> 5) + j) * 32) * 512 + (size_t)l * 8;
#pragma unroll
            for (int i = 0; i < 8; ++i) kr[i] = *(const f16x8*)(kpn + (size_t)i * 512);
        }
        // ---- combine l across 8 j-waves ----
        {
            float4 lv0 = *(float4*)&lbuf[q][0];
            float4 lv1 = *(float4*)&lbuf[q][4];
            l0_st = l0_st * alpha0 + ((lv0.x + lv0.y) + (lv0.z + lv0.w))
                                   + ((lv1.x + lv1.y) + (lv1.z + lv1.w));
            float4 lw0 = *(float4*)&lbuf[q + 32][0];
            float4 lw1 = *(float4*)&lbuf[q + 32][4];
            l1_st = l1_st * alpha1 + ((lw0.x + lw0.y) + (lw0.z + lw0.w))
                                   + ((lw1.x + lw1.y) + (lw1.z + lw1.w));
        }
        // ---- rescale O halves via abuf broadcast ----
        {
            float av0[4][4], av1[4][4];
#pragma unroll
            for (int g = 0; g < 4; ++g) {
                float4 a4 = *(float4*)&abuf[8 * g + 4 * lh];
                av0[g][0] = a4.x; av0[g][1] = a4.y; av0[g][2] = a4.z; av0[g][3] = a4.w;
                float4 b4 = *(float4*)&abuf[32 + 8 * g + 4 * lh];
                av1[g][0] = b4.x; av1[g][1] = b4.y; av1[g][2] = b4.z; av1[g][3] = b4.w;
            }
#pragma unroll
            for (int dt = 0; dt < 2; ++dt)
#pragma unroll
                for (int r = 0; r < 16; ++r) {
                    o[dt][r] *= av0[r >> 2][r & 3];
                    o[2 + dt][r] *= av1[r >> 2][r & 3];
                }
        }
        // ---- PV: O[64q][64d j-slice] += P * V; each V frag used 2x ----
        __builtin_amdgcn_s_setprio(1);
#pragma unroll
        for (int kk = 0; kk < 16; ++kk) {
            f16x8 v0 = vr[(kk & 3) * 2];
            f16x8 v1 = vr[(kk & 3) * 2 + 1];
            if (kk < 12) {
                vr[(kk & 3) * 2] = *(const f16x8*)(vpb + (size_t)(kk + 4) * 512);
                vr[(kk & 3) * 2 + 1] = *(const f16x8*)(vpb + (size_t)(128 + kk + 4) * 512);
            }
            f16x8 paf0 = *(f16x8*)(Pq + (((uint)q * 512 + (uint)(16 * kk + 8 * lh) * 2) ^ swz));
            f16x8 paf1 = *(f16x8*)(Pq + (((uint)(q + 32) * 512 + (uint)(16 * kk + 8 * lh) * 2) ^ swz));
            o[0] = MFMA32(paf0, v0, o[0]);
            o[1] = MFMA32(paf0, v1, o[1]);
            o[2] = MFMA32(paf1, v0, o[2]);
            o[3] = MFMA32(paf1, v1, o[3]);
        }
        __builtin_amdgcn_s_setprio(0);
    }
    __syncthreads();  // protect abuf reuse below against stragglers in PV
    if (l < 32) { abuf[q] = l0_st; abuf[q + 32] = l1_st; }
    if (PART && l < 32 && j == 0) {
        Ml[((size_t)bid * 64 + q) * 2 + 0] = m0_st;
        Ml[((size_t)bid * 64 + q) * 2 + 1] = l0_st;
        Ml[((size_t)bid * 64 + q + 32) * 2 + 0] = m1_st;
        Ml[((size_t)bid * 64 + q + 32) * 2 + 1] = l1_st;
    }
    __syncthreads();
    float iv0[4][4], iv1[4][4];
#pragma unroll
    for (int g = 0; g < 4; ++g) {
        float4 a4 = *(float4*)&abuf[8 * g + 4 * lh];
        iv0[g][0] = 1.f / a4.x; iv0[g][1] = 1.f / a4.y; iv0[g][2] = 1.f / a4.z; iv0[g][3] = 1.f / a4.w;
        float4 b4 = *(float4*)&abuf[32 + 8 * g + 4 * lh];
        iv1[g][0] = 1.f / b4.x; iv1[g][1] = 1.f / b4.y; iv1[g][2] = 1.f / b4.z; iv1[g][3] = 1.f / b4.w;
    }
    f16* op = PART ? (Opart + (size_t)bid * 64 * 512 + 64 * j)
                   : (AO + ((size_t)(b * 2048 + q0)) * 512 + 64 * j);
#pragma unroll
    for (int r = 0; r < 16; ++r) {
        int qr = (r & 3) + 8 * (r >> 2) + 4 * lh;
        float i0 = iv0[r >> 2][r & 3];
        float i1 = iv1[r >> 2][r & 3];
#pragma unroll
        for (int dt = 0; dt < 2; ++dt) {
            op[(size_t)qr * 512 + 32 * dt + q] = (f16)(o[dt][r] * i0);
            op[(size_t)(qr + 32) * 512 + 32 * dt + q] = (f16)(o[2 + dt][r] * i1);
        }
    }
}

// ---------------- split-K combine (NS partials per 64-row q-block) ----------------
template<int NS>
__global__ __launch_bounds__(256) void combineN(const f16* __restrict__ Opart, const float* __restrict__ Ml,
                                                f16* __restrict__ AO) {
    int gid = blockIdx.x * 256 + threadIdx.x;
    int row = gid >> 6, col0 = (gid & 63) * 8;
    int b = row >> 11, qq = row & 2047;
    int qb = qq >> 6, qr = qq & 63;
    int bids[NS];
    float m[NS], ll[NS];
#pragma unroll
    for (int s = 0; s < NS; ++s) {
        int t = qb * NS + s;
        bids[s] = (t >> 1) * 8 + 2 * b + (t & 1);
        m[s] = Ml[((size_t)bids[s] * 64 + qr) * 2];
        ll[s] = Ml[((size_t)bids[s] * 64 + qr) * 2 + 1];
    }
    float M = m[0];
#pragma unroll
    for (int s = 1; s < NS; ++s) M = fmaxf(M, m[s]);
    float c[NS], W = 0.f;
#pragma unroll
    for (int s = 0; s < NS; ++s) {
        c[s] = __expf(m[s] - M) * ll[s];
        W += c[s];
    }
    float invW = 1.f / W;
    float av[8] = {};
#pragma unroll
    for (int s = 0; s < NS; ++s) {
        f16x8 v = *(const f16x8*)&Opart[((size_t)bids[s] * 64 + qr) * 512 + col0];
        float cs = c[s] * invW;
#pragma unroll
        for (int jj = 0; jj < 8; ++jj) av[jj] += cs * (float)v[jj];
    }
    f16x8 o8;
#pragma unroll
    for (int jj = 0; jj < 8; ++jj) o8[jj] = (f16)av[jj];
    *(f16x8*)&AO[(size_t)row * 512 + col0] = o8;
}

// ---------------- launch ----------------
extern "C" void kernel_launch(void* const* d_in, const int* in_sizes, int n_in,
                              void* d_out, int out_size, void* d_ws, size_t ws_size,
                              hipStream_t stream) {
    (void)in_sizes; (void)n_in; (void)out_size;
    const float* x = (const float*)d_in[0];
    const float* qkv_w = (const float*)d_in[1];
    const float* qkv_b = (const float*)d_in[2];
    const float* out_w = (const float*)d_in[3];
    const float* out_b = (const float*)d_in[4];
    char* ws = (char*)d_ws;
    f16* xh    = (f16*)(ws + 0);
    f16* wqkvh = (f16*)(ws + 8388608);
    f16* wouth = (f16*)(ws + 9961472);
    f16* Qb    = (f16*)(ws + 10485760);
    f16* Kb    = (f16*)(ws + 18874368);  // packed K fragments, 8,388,608
    f16* Vt    = (f16*)(ws + 27262976);  // packed V fragments, 8,388,608
    f16* AO    = (f16*)(ws + 35651584);
    f16* Opart = (f16*)(ws + 44040192);               // 256*64*512*2 = 16,777,216
    float* Ml  = (float*)(ws + 44040192 + 16777216);  // 256*64*2*4 = 131,072
    const size_t NEED = 44040192ull + 16777216ull + 131072ull;

    cvt_all<<<5120, 256, 0, stream>>>(x, qkv_w, out_w, xh);

    gemm_nt<0><<<dim3(64, 12), 256, 0, stream>>>(xh, wqkvh, qkv_b, nullptr, Qb, Kb, Vt);

    if (ws_size >= NEED) {
        flash_attn<2, true><<<256, 512, 0, stream>>>(Qb, Kb, Vt, nullptr, Opart, Ml);
        combineN<2><<<2048, 256, 0, stream>>>(Opart, Ml, AO);
    } else {
        flash_attn<1, false><<<128, 512, 0, stream>>>(Qb, Kb, Vt, AO, nullptr, nullptr);
    }

    gemm_nt<1><<<dim3(64, 4), 256, 0, stream>>>(AO, wouth, out_b, (float*)d_out,
                                                nullptr, nullptr, nullptr);
}

// Round 14
// 111.543 us; speedup vs baseline: 1.1955x; 1.1955x over previous
//
#include <hip/hip_runtime.h>

typedef _Float16 f16;
typedef _Float16 f16x2 __attribute__((ext_vector_type(2)));
typedef _Float16 f16x4 __attribute__((ext_vector_type(4)));
typedef _Float16 f16x8 __attribute__((ext_vector_type(8)));
typedef float f32x4 __attribute__((ext_vector_type(4)));
typedef float f32x16 __attribute__((ext_vector_type(16)));

#define MFMA16(a, b, c) __builtin_amdgcn_mfma_f32_16x16x32_f16((a), (b), (c), 0, 0, 0)
#define MFMA32(a, b, c) __builtin_amdgcn_mfma_f32_32x32x16_f16((a), (b), (c), 0, 0, 0)

typedef const __attribute__((address_space(1))) void gv_t;
typedef __attribute__((address_space(3))) void lv_t;

// ---------------- fused fp32 -> f16 convert (x, qkv_w, out_w in one launch) ------
__global__ void cvt_all(const float* __restrict__ x, const float* __restrict__ qw,
                        const float* __restrict__ ow, f16* __restrict__ d) {
    int i = (blockIdx.x * 256 + threadIdx.x) * 4;   // flat f16-element index / 4
    const float* s;
    int off;
    if (i < 4194304) { s = x; off = i; }
    else if (i < 4980736) { s = qw; off = i - 4194304; }
    else { s = ow; off = i - 4980736; }
    float4 v = *(const float4*)(s + off);
    f16x4 o = {(f16)v.x, (f16)v.y, (f16)v.z, (f16)v.w};
    *(f16x4*)(d + i) = o;
}

// ---------------- NT GEMM, 128x128 tile, BK=32, dbuf LDS via global_load_lds ----
// MODE 0 epilogue packs K and V into MFMA-fragment-major layouts:
//   Kp[b][kb=s>>5][kc=d>>4][lane=(d>>3&1)*32+(s&31)][e=d&7]
//   Vp[b][db=d>>5][kw=s>>4][lane=(s>>3&1)*32+(d&31)][e=s&7]
template<int MODE>
__global__ __launch_bounds__(256, 3) void gemm_nt(const f16* __restrict__ A, const f16* __restrict__ W,
                                                  const float* __restrict__ bias, float* __restrict__ Cf,
                                                  f16* __restrict__ Qb, f16* __restrict__ Kb,
                                                  f16* __restrict__ Vt) {
    __shared__ f16 As[2][128 * 32];
    __shared__ f16 Bs[2][128 * 32];
    const int m0 = blockIdx.x * 128, n0 = blockIdx.y * 128;
    const int tid = threadIdx.x;
    const int w = tid >> 6, l = tid & 63;
    const int wm = w >> 1, wn = w & 1;
    const int lr = l & 15, lg = l >> 4;
    const int R = w * 16 + (l >> 2);
    const int ldsoff = w * 512;
    const int lidx = ldsoff + l * 8;
    const f16* ag = A + (size_t)(m0 + R) * 512 + (l & 3) * 8;
    const f16* bg = W + (size_t)(n0 + R) * 512 + (l & 3) * 8;
    (void)lidx;

#if __has_builtin(__builtin_amdgcn_global_load_lds)
#define GLDS(gp, lp) __builtin_amdgcn_global_load_lds((gv_t*)(gp), (lv_t*)(lp), 16, 0, 0)
#define STAGE(k0, buf) do {                                   \
        GLDS(ag + (k0), &As[buf][ldsoff]);                    \
        GLDS(ag + 64 * 512 + (k0), &As[buf][ldsoff + 2048]);  \
        GLDS(bg + (k0), &Bs[buf][ldsoff]);                    \
        GLDS(bg + 64 * 512 + (k0), &Bs[buf][ldsoff + 2048]);  \
    } while (0)
#else
#define STAGE(k0, buf) do {                                                      \
        *(f16x8*)&As[buf][lidx] = *(const f16x8*)(ag + (k0));                    \
        *(f16x8*)&As[buf][lidx + 2048] = *(const f16x8*)(ag + 64 * 512 + (k0));  \
        *(f16x8*)&Bs[buf][lidx] = *(const f16x8*)(bg + (k0));                    \
        *(f16x8*)&Bs[buf][lidx + 2048] = *(const f16x8*)(bg + 64 * 512 + (k0));  \
    } while (0)
#endif

    f32x4 acc[4][4] = {};
    STAGE(0, 0);
    __syncthreads();
    int cur = 0;
    for (int k0 = 0; k0 < 512; k0 += 32) {
        if (k0 + 32 < 512) STAGE(k0 + 32, cur ^ 1);
        f16x8 af[4], bf[4];
#pragma unroll
        for (int i = 0; i < 4; ++i) af[i] = *(f16x8*)&As[cur][(64 * wm + 16 * i + lr) * 32 + lg * 8];
#pragma unroll
        for (int i = 0; i < 4; ++i) bf[i] = *(f16x8*)&Bs[cur][(64 * wn + 16 * i + lr) * 32 + lg * 8];
        __builtin_amdgcn_s_setprio(1);
#pragma unroll
        for (int mf = 0; mf < 4; ++mf)
#pragma unroll
            for (int nf = 0; nf < 4; ++nf) acc[mf][nf] = MFMA16(af[mf], bf[nf], acc[mf][nf]);
        __builtin_amdgcn_s_setprio(0);
        __syncthreads();
        cur ^= 1;
    }
#pragma unroll
    for (int mf = 0; mf < 4; ++mf)
#pragma unroll
        for (int nf = 0; nf < 4; ++nf)
#pragma unroll
            for (int r = 0; r < 4; ++r) {
                int rr = 64 * wm + 16 * mf + 4 * lg + r;
                int cc = 64 * wn + 16 * nf + lr;
                int m = m0 + rr, e = n0 + cc;
                float val = acc[mf][nf][r] + bias[e];
                if (MODE == 0) {
                    int bb = m >> 11, s = m & 2047;
                    if (e < 512) {
                        Qb[((size_t)bb * 2048 + s) * 512 + e] = (f16)(val * 0.04419417382415922f);
                    } else if (e < 1024) {
                        int d = e - 512;
                        Kb[((((size_t)bb * 64 + (s >> 5)) * 32 + (d >> 4)) * 64
                            + ((d >> 3) & 1) * 32 + (s & 31)) * 8 + (d & 7)] = (f16)val;
                    } else {
                        int d = e - 1024;
                        Vt[((((size_t)bb * 16 + (d >> 5)) * 128 + (s >> 4)) * 64
                            + ((s >> 3) & 1) * 32 + (d & 31)) * 8 + (s & 7)] = (f16)val;
                    }
                } else {
                    Cf[(size_t)m * 512 + e] = val;
                }
            }
#undef STAGE
}

// ---------------- flash attention: 8 waves, QBLK=32, KEYTILE=256, 32x32 MFMA ----
// r10-proven config (65us): kt-top batch preload of K ring(8) + V pairs(8),
// ring refills inside QK^T/PV, NSPLIT=2 (512 WGs), no setprio, no cross-kt reload.
template<int NSPLIT, bool PART>
__global__ __launch_bounds__(512, 2) void flash_attn(const f16* __restrict__ Qb, const f16* __restrict__ Kb,
                                                     const f16* __restrict__ Vt, f16* __restrict__ AO,
                                                     f16* __restrict__ Opart, float* __restrict__ Ml) {
    __shared__ f16 Qs[32 * 512];   // [row][chunk^(row&7)] on 16B chunks
    __shared__ f16 P_lds[32 * 256];
    __shared__ float mbuf[32][8];
    __shared__ float lbuf[32][8];
    __shared__ float abuf[32];

    const int bid = blockIdx.x;
    const int xcd = bid & 7, slot = bid >> 3;
    const int b = xcd >> 1;
    const int t = slot * 2 + (xcd & 1);      // 0 .. 64*NSPLIT-1
    const int q0 = (t / NSPLIT) * 32;
    const int ks = t % NSPLIT;
    const int SPLITLEN = 2048 / NSPLIT;
    const int nkt = SPLITLEN / 256;

    const int tid = threadIdx.x;
    const int j = tid >> 6, l = tid & 63;
    const int q = l & 31, lh = l >> 5;

    const f16* Qg = Qb + ((size_t)b * 2048 + q0) * 512;
    const f16* Kg = Kb + ((size_t)b * 64 + (size_t)ks * (SPLITLEN / 32)) * 32 * 512;
    const f16* Vg = Vt + (size_t)b * 16 * 128 * 512 + (size_t)(ks * (SPLITLEN / 16)) * 512;

    // stage Q tile [32][512] into swizzled LDS (coalesced 16B per lane)
    for (int i = tid; i < 2048; i += 512) {
        int r = i >> 6, ch = i & 63;
        *(f16x8*)&Qs[r * 512 + ((ch ^ (r & 7)) * 8)] = *(const f16x8*)&Qg[(size_t)r * 512 + ch * 8];
    }

    f32x16 o[2] = {};
    float m_st = -1e30f, l_st = 0.f;
    char* Pq = (char*)&P_lds[0];
    const uint swz = ((uint)(q & 15)) << 4;
    const int qbase = q * 512, qx = q & 7;
    __syncthreads();

    for (int kt = 0; kt < nkt; ++kt) {
        const int key0 = kt * 256;
        const f16* kp = Kg + ((size_t)((key0 >> 5) + j) * 32) * 512 + (size_t)l * 8;
        const f16* vpb = Vg + ((size_t)(2 * j) * 128 + (key0 >> 4)) * 512 + (size_t)l * 8;
        // ---- batch preload: K ring (8) + V pairs for kk=0..3 (8) ----
        f16x8 kr[8], vr[8];
#pragma unroll
        for (int i = 0; i < 8; ++i) kr[i] = *(const f16x8*)(kp + (size_t)i * 512);
#pragma unroll
        for (int i = 0; i < 4; ++i) {
            vr[2 * i] = *(const f16x8*)(vpb + (size_t)i * 512);
            vr[2 * i + 1] = *(const f16x8*)(vpb + (size_t)(128 + i) * 512);
        }
        // ---- QK^T (swapped): S^T[32 keys j-slice][32 q]; K ring prefetch ----
        f32x16 sA = {}, sB = {};
#pragma unroll
        for (int kc = 0; kc < 32; kc += 2) {
            f16x8 k0 = kr[kc & 7];
            f16x8 k1 = kr[(kc & 7) + 1];
            if (kc < 24) {
                kr[kc & 7] = *(const f16x8*)(kp + (size_t)(kc + 8) * 512);
                kr[(kc & 7) + 1] = *(const f16x8*)(kp + (size_t)(kc + 9) * 512);
            }
            f16x8 q0f = *(f16x8*)&Qs[qbase + (((2 * kc + lh) ^ qx) * 8)];
            f16x8 q1f = *(f16x8*)&Qs[qbase + (((2 * kc + 2 + lh) ^ qx) * 8)];
            sA = MFMA32(k0, q0f, sA);
            sB = MFMA32(k1, q1f, sB);
        }
        float s[16];
#pragma unroll
        for (int r = 0; r < 16; ++r) s[r] = sA[r] + sB[r];
        // ---- in-register partial max over own 32 keys ----
        float mt = s[0];
#pragma unroll
        for (int r = 1; r < 16; ++r) mt = fmaxf(mt, s[r]);
        mt = fmaxf(mt, __shfl_xor(mt, 32));
        if (l < 32) mbuf[q][j] = mt;
        __syncthreads();  // barrier 1
        float mnew = m_st;
        {
            float4 mv0 = *(float4*)&mbuf[q][0];
            float4 mv1 = *(float4*)&mbuf[q][4];
            mnew = fmaxf(mnew, fmaxf(fmaxf(mv0.x, mv0.y), fmaxf(mv0.z, mv0.w)));
            mnew = fmaxf(mnew, fmaxf(fmaxf(mv1.x, mv1.y), fmaxf(mv1.z, mv1.w)));
        }
        float alpha = __expf(m_st - mnew);
        if (l < 32) abuf[q] = alpha;
        float ps = 0.f;
#pragma unroll
        for (int r = 0; r < 16; ++r) {
            s[r] = __expf(s[r] - mnew);
            ps += s[r];
        }
        ps += __shfl_xor(ps, 32);
        if (l < 32) lbuf[q][j] = ps;
        // pack P -> P_lds[q][key], XOR-swizzled, f16x4 chunks (keys e+8i+4lh+32j)
        {
            const uint rowb = (uint)q * 512;
#pragma unroll
            for (int i = 0; i < 4; ++i) {
                int key = 8 * i + 4 * lh + 32 * j;
                f16x4 pk = {(f16)s[4 * i], (f16)s[4 * i + 1], (f16)s[4 * i + 2], (f16)s[4 * i + 3]};
                *(f16x4*)(Pq + ((rowb + (uint)key * 2) ^ swz)) = pk;
            }
        }
        m_st = mnew;
        __syncthreads();  // barrier 2
        // ---- combine l across 8 j-waves ----
        {
            float4 lv0 = *(float4*)&lbuf[q][0];
            float4 lv1 = *(float4*)&lbuf[q][4];
            l_st = l_st * alpha + ((lv0.x + lv0.y) + (lv0.z + lv0.w))
                                + ((lv1.x + lv1.y) + (lv1.z + lv1.w));
        }
        // ---- rescale O: alpha per O-reg's q-row via abuf broadcast ----
        float av[4][4];
#pragma unroll
        for (int g = 0; g < 4; ++g) {
            float4 a4 = *(float4*)&abuf[8 * g + 4 * lh];
            av[g][0] = a4.x; av[g][1] = a4.y; av[g][2] = a4.z; av[g][3] = a4.w;
        }
#pragma unroll
        for (int dt = 0; dt < 2; ++dt)
#pragma unroll
            for (int r = 0; r < 16; ++r) o[dt][r] *= av[r >> 2][r & 3];
        // ---- PV: O[32q][64d j-slice] += P[32q][256k] * V; V ring prefetch ----
#pragma unroll
        for (int kk = 0; kk < 16; ++kk) {
            f16x8 v0 = vr[(kk & 3) * 2];
            f16x8 v1 = vr[(kk & 3) * 2 + 1];
            if (kk < 12) {
                vr[(kk & 3) * 2] = *(const f16x8*)(vpb + (size_t)(kk + 4) * 512);
                vr[(kk & 3) * 2 + 1] = *(const f16x8*)(vpb + (size_t)(128 + kk + 4) * 512);
            }
            f16x8 paf = *(f16x8*)(Pq + (((uint)q * 512 + (uint)(16 * kk + 8 * lh) * 2) ^ swz));
            o[0] = MFMA32(paf, v0, o[0]);
            o[1] = MFMA32(paf, v1, o[1]);
        }
    }
    __syncthreads();  // protect abuf reuse below against stragglers in PV
    if (l < 32) abuf[q] = l_st;
    if (PART && l < 32 && j == 0) {
        Ml[((size_t)bid * 32 + q) * 2 + 0] = m_st;
        Ml[((size_t)bid * 32 + q) * 2 + 1] = l_st;
    }
    __syncthreads();
    float iv[4][4];
#pragma unroll
    for (int g = 0; g < 4; ++g) {
        float4 a4 = *(float4*)&abuf[8 * g + 4 * lh];
        iv[g][0] = 1.f / a4.x; iv[g][1] = 1.f / a4.y; iv[g][2] = 1.f / a4.z; iv[g][3] = 1.f / a4.w;
    }
    f16* op = PART ? (Opart + (size_t)bid * 32 * 512 + 64 * j)
                   : (AO + ((size_t)(b * 2048 + q0)) * 512 + 64 * j);
#pragma unroll
    for (int r = 0; r < 16; ++r) {
        int qr = (r & 3) + 8 * (r >> 2) + 4 * lh;
        float inv = iv[r >> 2][r & 3];
#pragma unroll
        for (int dt = 0; dt < 2; ++dt)
            op[(size_t)qr * 512 + 32 * dt + q] = (f16)(o[dt][r] * inv);
    }
}

// ---------------- split-K combine (NS partials per 32-row q-block) ----------------
template<int NS>
__global__ __launch_bounds__(256) void combineN(const f16* __restrict__ Opart, const float* __restrict__ Ml,
                                                f16* __restrict__ AO) {
    int gid = blockIdx.x * 256 + threadIdx.x;
    int row = gid >> 6, col0 = (gid & 63) * 8;
    int b = row >> 11, qq = row & 2047;
    int qb = qq >> 5, qr = qq & 31;
    int bids[NS];
    float m[NS], ll[NS];
#pragma unroll
    for (int s = 0; s < NS; ++s) {
        int t = qb * NS + s;
        bids[s] = (t >> 1) * 8 + 2 * b + (t & 1);
        m[s] = Ml[((size_t)bids[s] * 32 + qr) * 2];
        ll[s] = Ml[((size_t)bids[s] * 32 + qr) * 2 + 1];
    }
    float M = m[0];
#pragma unroll
    for (int s = 1; s < NS; ++s) M = fmaxf(M, m[s]);
    float c[NS], W = 0.f;
#pragma unroll
    for (int s = 0; s < NS; ++s) {
        c[s] = __expf(m[s] - M) * ll[s];
        W += c[s];
    }
    float invW = 1.f / W;
    float av[8] = {};
#pragma unroll
    for (int s = 0; s < NS; ++s) {
        f16x8 v = *(const f16x8*)&Opart[((size_t)bids[s] * 32 + qr) * 512 + col0];
        float cs = c[s] * invW;
#pragma unroll
        for (int jj = 0; jj < 8; ++jj) av[jj] += cs * (float)v[jj];
    }
    f16x8 o8;
#pragma unroll
    for (int jj = 0; jj < 8; ++jj) o8[jj] = (f16)av[jj];
    *(f16x8*)&AO[(size_t)row * 512 + col0] = o8;
}

// ---------------- launch ----------------
extern "C" void kernel_launch(void* const* d_in, const int* in_sizes, int n_in,
                              void* d_out, int out_size, void* d_ws, size_t ws_size,
                              hipStream_t stream) {
    (void)in_sizes; (void)n_in; (void)out_size;
    const float* x = (const float*)d_in[0];
    const float* qkv_w = (const float*)d_in[1];
    const float* qkv_b = (const float*)d_in[2];
    const float* out_w = (const float*)d_in[3];
    const float* out_b = (const float*)d_in[4];
    char* ws = (char*)d_ws;
    f16* xh    = (f16*)(ws + 0);
    f16* wqkvh = (f16*)(ws + 8388608);
    f16* wouth = (f16*)(ws + 9961472);
    f16* Qb    = (f16*)(ws + 10485760);
    f16* Kb    = (f16*)(ws + 18874368);  // packed K fragments, 8,388,608
    f16* Vt    = (f16*)(ws + 27262976);  // packed V fragments, 8,388,608
    f16* AO    = (f16*)(ws + 35651584);
    f16* Opart = (f16*)(ws + 44040192);               // 512*32*512*2 = 16,777,216
    float* Ml  = (float*)(ws + 44040192 + 16777216);  // 512*32*2*4 = 131,072
    const size_t NEED = 44040192ull + 16777216ull + 131072ull;

    cvt_all<<<5120, 256, 0, stream>>>(x, qkv_w, out_w, xh);

    gemm_nt<0><<<dim3(64, 12), 256, 0, stream>>>(xh, wqkvh, qkv_b, nullptr, Qb, Kb, Vt);

    if (ws_size >= NEED) {
        flash_attn<2, true><<<512, 512, 0, stream>>>(Qb, Kb, Vt, nullptr, Opart, Ml);
        combineN<2><<<2048, 256, 0, stream>>>(Opart, Ml, AO);
    } else {
        flash_attn<1, false><<<256, 512, 0, stream>>>(Qb, Kb, Vt, AO, nullptr, nullptr);
    }

    gemm_nt<1><<<dim3(64, 4), 256, 0, stream>>>(AO, wouth, out_b, (float*)d_out,
                                                nullptr, nullptr, nullptr);
}